// Round 5
// baseline (125.610 us; speedup 1.0000x reference)
//
#include <hip/hip_runtime.h>
#include <math.h>

#define N_    32
#define C_    512
#define P_    1024
#define KG_   10
#define KV_   8
#define PBLK_ 64
#define NPB_  (P_ / PBLK_)   // 16
#define PS_   81             // part row stride, conflict-free

// ---------------------------------------------------------------------------
// K1: partial logits. Block = (n, pb, ch): reduces c in [ch*256,(ch+1)*256).
// 512 threads = 8 waves; wave cg owns 32 uniform c's (w -> scalar s_loads);
// lane <-> p (64 contiguous, 256 B/load-instr). Grid N*32=1024 blocks x 8
// waves = 32 waves/CU (max occupancy) -> 2x memory parallelism vs R4.
// Output: plg[(n*16+pb)*2+ch][k][64p] partial sums.
// ---------------------------------------------------------------------------
__global__ __launch_bounds__(512, 8) void vlad_logits_p(
    const float* __restrict__ x, const float* __restrict__ w,
    float* __restrict__ plg) {
  __shared__ float part[PBLK_ * PS_];   // 20736 B
  const int t  = threadIdx.x;
  const int pl = t & 63;
  const int cg = __builtin_amdgcn_readfirstlane(t >> 6);  // 0..7
  const int bx = blockIdx.x;
  const int n  = bx >> 5;
  const int pb = (bx >> 1) & 15;
  const int ch = bx & 1;
  const int p0 = pb * PBLK_;
  const int c0 = ch * 256 + cg * 32;

  const float* xp = x + ((size_t)n * C_ + c0) * P_ + p0 + pl;
  const float* wp = w + c0;

  float acc[KG_];
#pragma unroll
  for (int k = 0; k < KG_; ++k) acc[k] = 0.f;

#pragma unroll 8
  for (int i = 0; i < 32; ++i) {
    const float xv = xp[(size_t)i * P_];       // coalesced, 32 indep loads
#pragma unroll
    for (int k = 0; k < KG_; ++k) acc[k] += xv * wp[k * C_ + i];  // s_load w
  }

#pragma unroll
  for (int k = 0; k < KG_; ++k) part[pl * PS_ + cg * KG_ + k] = acc[k];
  __syncthreads();

  if (t < 64) {
    const size_t row = (size_t)((n * NPB_ + pb) * 2 + ch) * KG_ * 64;
#pragma unroll
    for (int k = 0; k < KG_; ++k) {
      float s = 0.f;
#pragma unroll
      for (int g = 0; g < 8; ++g) s += part[t * PS_ + g * KG_ + k];
      plg[row + k * 64 + t] = s;               // coalesced
    }
  }
}

// ---------------------------------------------------------------------------
// K2: combine c-halves + bias, softmax over 10, write a + per-(n,pb) asum.
// Grid N*16=512 blocks x 64 threads (lane <-> p). All loads L2-hot, tiny.
// ---------------------------------------------------------------------------
__global__ __launch_bounds__(64) void vlad_softmax2(
    const float* __restrict__ plg, const float* __restrict__ bias,
    float* __restrict__ a_ws, float* __restrict__ asum_blk) {
  const int t  = threadIdx.x;
  const int n  = blockIdx.x >> 4;
  const int pb = blockIdx.x & 15;
  const size_t r0 = (size_t)((n * NPB_ + pb) * 2 + 0) * KG_ * 64;
  const size_t r1 = (size_t)((n * NPB_ + pb) * 2 + 1) * KG_ * 64;

  float l[KG_];
  float m = -1e30f;
#pragma unroll
  for (int k = 0; k < KG_; ++k) {
    l[k] = plg[r0 + k * 64 + t] + plg[r1 + k * 64 + t] + bias[k];
    m = fmaxf(m, l[k]);
  }
  float sum = 0.f;
#pragma unroll
  for (int k = 0; k < KG_; ++k) { l[k] = __expf(l[k] - m); sum += l[k]; }
  const float inv = 1.f / sum;
#pragma unroll
  for (int k = 0; k < KV_; ++k) {
    const float a = l[k] * inv;
    a_ws[((size_t)n * KV_ + k) * P_ + pb * PBLK_ + t] = a;
    float s = a;
    s += __shfl_xor(s, 1, 64);  s += __shfl_xor(s, 2, 64);
    s += __shfl_xor(s, 4, 64);  s += __shfl_xor(s, 8, 64);
    s += __shfl_xor(s, 16, 64); s += __shfl_xor(s, 32, 64);
    if (t == 0) asum_blk[(n * NPB_ + pb) * KV_ + k] = s;
  }
}

// ---------------------------------------------------------------------------
// K3: partial ax over a 512-p half. Block = (n, cb, ph); wave owns 4 c's;
// lanes <-> p via float4. Grid N*64 = 2048 blocks of 256.
// ---------------------------------------------------------------------------
__global__ __launch_bounds__(256) void vlad_ax2(
    const float* __restrict__ x, const float* __restrict__ a_ws,
    float* __restrict__ axp) {
  const int bx   = blockIdx.x;
  const int n    = bx >> 6;
  const int cb   = (bx >> 1) & 31;
  const int ph   = bx & 1;
  const int lane = threadIdx.x & 63;
  const int wv   = threadIdx.x >> 6;
  const int c0   = cb * 16 + wv * 4;

  const float* ap = a_ws + (size_t)n * KV_ * P_ + ph * 512;
  const float* xp = x + (size_t)n * C_ * P_ + ph * 512;

  float acc[4][8];
#pragma unroll
  for (int cc = 0; cc < 4; ++cc)
#pragma unroll
    for (int k = 0; k < 8; ++k) acc[cc][k] = 0.f;

#pragma unroll
  for (int i = 0; i < 2; ++i) {
    const int pb = i * 256 + lane * 4;
    float4 a4[8];
#pragma unroll
    for (int k = 0; k < 8; ++k)
      a4[k] = *reinterpret_cast<const float4*>(ap + (size_t)k * P_ + pb);
#pragma unroll
    for (int cc = 0; cc < 4; ++cc) {
      float4 x4 = *reinterpret_cast<const float4*>(xp + (size_t)(c0 + cc) * P_ + pb);
#pragma unroll
      for (int k = 0; k < 8; ++k)
        acc[cc][k] += x4.x * a4[k].x + x4.y * a4[k].y
                    + x4.z * a4[k].z + x4.w * a4[k].w;
    }
  }

  float v[32];
#pragma unroll
  for (int cc = 0; cc < 4; ++cc)
#pragma unroll
    for (int k = 0; k < 8; ++k) v[cc * 8 + k] = acc[cc][k];

  {  const bool hi = lane & 1;
#pragma unroll
    for (int j = 0; j < 16; ++j) {
      float send = hi ? v[j] : v[j + 16];
      float keep = hi ? v[j + 16] : v[j];
      v[j] = keep + __shfl_xor(send, 1, 64);
    } }
  {  const bool hi = lane & 2;
#pragma unroll
    for (int j = 0; j < 8; ++j) {
      float send = hi ? v[j] : v[j + 8];
      float keep = hi ? v[j + 8] : v[j];
      v[j] = keep + __shfl_xor(send, 2, 64);
    } }
  {  const bool hi = lane & 4;
#pragma unroll
    for (int j = 0; j < 4; ++j) {
      float send = hi ? v[j] : v[j + 4];
      float keep = hi ? v[j + 4] : v[j];
      v[j] = keep + __shfl_xor(send, 4, 64);
    } }
  {  const bool hi = lane & 8;
#pragma unroll
    for (int j = 0; j < 2; ++j) {
      float send = hi ? v[j] : v[j + 2];
      float keep = hi ? v[j + 2] : v[j];
      v[j] = keep + __shfl_xor(send, 8, 64);
    } }
  {  const bool hi = lane & 16;
    float send = hi ? v[0] : v[1];
    float keep = hi ? v[1] : v[0];
    v[0] = keep + __shfl_xor(send, 16, 64);
  }
  v[0] += __shfl_xor(v[0], 32, 64);

  if (lane < 32) {
    const int o = ((lane & 1) << 4) | ((lane & 2) << 2) | (lane & 4)
                | (((lane >> 3) & 1) << 1) | ((lane >> 4) & 1);
    const int cc = o >> 3;
    const int k  = o & 7;
    axp[((size_t)(n * 2 + ph) * KV_ + k) * C_ + (c0 + cc)] = v[0];
  }
}

// ---------------------------------------------------------------------------
// K4: sum p-halves, asum, residual, L2 normalize, write. N*8 blocks of 256.
// ---------------------------------------------------------------------------
__global__ __launch_bounds__(256) void vlad_fin(
    const float* __restrict__ axp, const float* __restrict__ asum_blk,
    const float* __restrict__ centers, float* __restrict__ out) {
  __shared__ float sred[4];
  const int n = blockIdx.x >> 3;
  const int k = blockIdx.x & 7;
  const int t = threadIdx.x, lane = t & 63, wv = t >> 6;

  float asv = 0.f;
#pragma unroll
  for (int pb = 0; pb < NPB_; ++pb)
    asv += asum_blk[(n * NPB_ + pb) * KV_ + k];

  const int c = t * 2;
  const float2 a0 = *reinterpret_cast<const float2*>(
      &axp[((size_t)(n * 2 + 0) * KV_ + k) * C_ + c]);
  const float2 a1 = *reinterpret_cast<const float2*>(
      &axp[((size_t)(n * 2 + 1) * KV_ + k) * C_ + c]);
  const float2 ct = *reinterpret_cast<const float2*>(&centers[k * C_ + c]);
  const float r0 = (a0.x + a1.x) - asv * ct.x;
  const float r1 = (a0.y + a1.y) - asv * ct.y;

  float ss = r0 * r0 + r1 * r1;
#pragma unroll
  for (int d = 1; d < 64; d <<= 1) ss += __shfl_xor(ss, d, 64);
  if (lane == 0) sred[wv] = ss;
  __syncthreads();
  const float tot = (sred[0] + sred[1]) + (sred[2] + sred[3]);
  const float inv = 1.f / fmaxf(sqrtf(tot), 1e-12f);

  out[(size_t)n * (KV_ * C_) + k * C_ + c]     = r0 * inv;
  out[(size_t)n * (KV_ * C_) + k * C_ + c + 1] = r1 * inv;
}

extern "C" void kernel_launch(void* const* d_in, const int* in_sizes, int n_in,
                              void* d_out, int out_size, void* d_ws, size_t ws_size,
                              hipStream_t stream) {
  const float* x       = (const float*)d_in[0];
  const float* conv_w  = (const float*)d_in[1];
  const float* conv_b  = (const float*)d_in[2];
  const float* centers = (const float*)d_in[3];
  float* out = (float*)d_out;

  float* plg      = (float*)d_ws;                             // 2.62 MB
  float* a_ws     = plg + (size_t)N_ * NPB_ * 2 * KG_ * 64;   // 1 MB
  float* axp      = a_ws + (size_t)N_ * KV_ * P_;             // 1 MB
  float* asum_blk = axp + (size_t)2 * N_ * KV_ * C_;          // 16 KB

  hipLaunchKernelGGL(vlad_logits_p, dim3(N_ * 32), dim3(512), 0, stream,
                     x, conv_w, plg);
  hipLaunchKernelGGL(vlad_softmax2, dim3(N_ * NPB_), dim3(64), 0, stream,
                     plg, conv_b, a_ws, asum_blk);
  hipLaunchKernelGGL(vlad_ax2,     dim3(N_ * 64), dim3(256), 0, stream,
                     x, a_ws, axp);
  hipLaunchKernelGGL(vlad_fin,     dim3(N_ * KV_), dim3(256), 0, stream,
                     axp, asum_blk, centers, out);
}